// Round 1
// baseline (680.720 us; speedup 1.0000x reference)
//
#include <hip/hip_runtime.h>
#include <math.h>

// Problem constants (fixed by setup_inputs): B=256, K=512, D=1024, T=0.07
#define B_N 256
#define K_N 512
#define D_N 1024
#define INV_T 14.285714285714286   // 1/0.07 in double

// ws layout:
//   [0,    2048): double pos_part[256]   (zeroed)
//   [2048, 2056): double fgsum           (zeroed)
//   [2112, 3136): float  inv_norm[256]   (fully written by kernel 1)

// Kernel 1: per-row inverse norm of bg_img + fg logit exp-sum.
// One block per b; 256 threads x float4 covers D=1024.
__global__ __launch_bounds__(256) void norm_fg_kernel(
    const float* __restrict__ bg_img, const float* __restrict__ fg_pro,
    double* __restrict__ fgsum, float* __restrict__ inv_norm)
{
  const int b = blockIdx.x;
  const int t = threadIdx.x;
  const float4* a4 = (const float4*)(bg_img + (size_t)b * D_N);
  const float4* f4 = (const float4*)(fg_pro + (size_t)b * D_N);
  float4 a = a4[t];
  float4 f = f4[t];
  float ss = a.x*a.x + a.y*a.y + a.z*a.z + a.w*a.w;
  float fd = a.x*f.x + a.y*f.y + a.z*f.z + a.w*f.w;
  #pragma unroll
  for (int off = 32; off > 0; off >>= 1) {
    ss += __shfl_xor(ss, off);
    fd += __shfl_xor(fd, off);
  }
  __shared__ float sss[4], sfd[4];
  const int wave = t >> 6;
  if ((t & 63) == 0) { sss[wave] = ss; sfd[wave] = fd; }
  __syncthreads();
  if (t == 0) {
    float ssum = (sss[0] + sss[1]) + (sss[2] + sss[3]);
    float fsum = (sfd[0] + sfd[1]) + (sfd[2] + sfd[3]);
    double inv = 1.0 / sqrt((double)ssum);
    inv_norm[b] = (float)inv;
    double fl = (double)fsum * inv * INV_T;
    atomicAdd(fgsum, exp(fl));
  }
}

// Kernel 2: the 512 MiB stream. One wave handles 4 consecutive (b,k) rows
// (all same b since 512 % 4 == 0). Lane i loads float4 at element 4*i ->
// 1 KiB coalesced segments. A-row fragment kept in registers across the
// 4 rows. Butterfly reduce, lane-0 expf, double accumulate, per-block
// combine, atomic into 256 partial slots.
__global__ __launch_bounds__(256) void dot_exp_kernel(
    const float* __restrict__ bg_img, const float* __restrict__ bg_pro,
    const float* __restrict__ inv_norm, double* __restrict__ pos_part)
{
  const int lane = threadIdx.x & 63;
  const int wib  = threadIdx.x >> 6;                 // wave in block (0..3)
  const int gwave = blockIdx.x * 4 + wib;            // 32768 waves total
  const int p0 = gwave * 4;                          // first of 4 pairs
  const int b = p0 >> 9;                             // K = 512

  const float4* a4 = (const float4*)(bg_img + (size_t)b * D_N);
  const float4 a0 = a4[lane];
  const float4 a1 = a4[lane + 64];
  const float4 a2 = a4[lane + 128];
  const float4 a3 = a4[lane + 192];
  const float inv = inv_norm[b];
  const float invt_f = (float)INV_T;

  double acc = 0.0;
  #pragma unroll
  for (int j = 0; j < 4; ++j) {
    const float4* p4 = (const float4*)(bg_pro + (size_t)(p0 + j) * D_N);
    float4 x0 = p4[lane];
    float4 x1 = p4[lane + 64];
    float4 x2 = p4[lane + 128];
    float4 x3 = p4[lane + 192];
    float s = a0.x*x0.x + a0.y*x0.y + a0.z*x0.z + a0.w*x0.w;
    s += a1.x*x1.x + a1.y*x1.y + a1.z*x1.z + a1.w*x1.w;
    s += a2.x*x2.x + a2.y*x2.y + a2.z*x2.z + a2.w*x2.w;
    s += a3.x*x3.x + a3.y*x3.y + a3.z*x3.z + a3.w*x3.w;
    #pragma unroll
    for (int off = 32; off > 0; off >>= 1) s += __shfl_xor(s, off);
    if (lane == 0) acc += (double)expf(s * inv * invt_f);
  }

  __shared__ double wacc[4];
  if (lane == 0) wacc[wib] = acc;
  __syncthreads();
  if (threadIdx.x == 0) {
    double tsum = (wacc[0] + wacc[1]) + (wacc[2] + wacc[3]);
    atomicAdd(&pos_part[blockIdx.x & 255], tsum);
  }
}

// Kernel 3: final scalar.
__global__ __launch_bounds__(256) void finalize_kernel(
    const double* __restrict__ pos_part, const double* __restrict__ fgsum,
    float* __restrict__ out)
{
  const int t = threadIdx.x;
  double v = pos_part[t];
  #pragma unroll
  for (int off = 32; off > 0; off >>= 1) v += __shfl_xor(v, off);
  __shared__ double w[4];
  if ((t & 63) == 0) w[t >> 6] = v;
  __syncthreads();
  if (t == 0) {
    double possum = (w[0] + w[1]) + (w[2] + w[3]);
    double pos = possum / (double)K_N;     // sum_b mean_k
    double r = *fgsum / pos;               // (neg - pos)/pos
    out[0] = (float)log1p(r);              // -log(pos/neg) = log1p(r)
  }
}

extern "C" void kernel_launch(void* const* d_in, const int* in_sizes, int n_in,
                              void* d_out, int out_size, void* d_ws, size_t ws_size,
                              hipStream_t stream) {
  const float* bg_img = (const float*)d_in[0];   // (B, D)
  const float* fg_pro = (const float*)d_in[1];   // (B, D)
  const float* bg_pro = (const float*)d_in[2];   // (B, K, D)

  char* ws = (char*)d_ws;
  double* pos_part = (double*)(ws);           // 256 doubles
  double* fgsum    = (double*)(ws + 2048);    // 1 double
  float*  inv_norm = (float*)(ws + 2112);     // 256 floats

  hipMemsetAsync(d_ws, 0, 2056, stream);

  norm_fg_kernel<<<B_N, 256, 0, stream>>>(bg_img, fg_pro, fgsum, inv_norm);

  // 131072 (b,k) rows / (4 waves/block * 4 rows/wave) = 8192 blocks
  dot_exp_kernel<<<(B_N * K_N) / 16, 256, 0, stream>>>(bg_img, bg_pro, inv_norm, pos_part);

  finalize_kernel<<<1, 256, 0, stream>>>(pos_part, fgsum, (float*)d_out);
}